// Round 4
// baseline (765.099 us; speedup 1.0000x reference)
//
#include <hip/hip_runtime.h>

// Problem constants
#define B_   2
#define S_   2048
#define D_   2048
#define H_   16
#define HKV_ 4
#define HD_  128
#define SCALE_ 0.08838834764831845f  // 128^-0.5

typedef unsigned short u16;
typedef unsigned int u32;
typedef __attribute__((ext_vector_type(4))) float  f32x4;
typedef __attribute__((ext_vector_type(8))) __bf16 bf16x8;

__device__ __forceinline__ u16 f2b(float f) {
  u32 u = __builtin_bit_cast(u32, f);
  u += 0x7fffu + ((u >> 16) & 1u);   // round-to-nearest-even
  return (u16)(u >> 16);
}
__device__ __forceinline__ float b2f(u16 v) {
  return __builtin_bit_cast(float, (u32)v << 16);
}

// ---------------- fp32 -> bf16 elementwise (x) ----------------
__global__ void k_f2b(const float* __restrict__ in, u16* __restrict__ out) {
  size_t i = (size_t)blockIdx.x * 256 + threadIdx.x;
  float4 v = reinterpret_cast<const float4*>(in)[i];
  ushort4 o;
  o.x = f2b(v.x); o.y = f2b(v.y); o.z = f2b(v.z); o.w = f2b(v.w);
  reinterpret_cast<ushort4*>(out)[i] = o;
}

// ---------------- tiny init: zero the 8 k-norm slots ----------------
__global__ void k_init8(u32* __restrict__ p) {
  if (threadIdx.x < 8) p[threadIdx.x] = 0u;
}

// ---------------- W[K][N] fp32 -> Wt[N][K] bf16 (tiled transpose) ----------------
__global__ void k_wT(const float* __restrict__ W, u16* __restrict__ Wt, int K, int N) {
  __shared__ float t[32][33];
  int n0 = blockIdx.x * 32, k0 = blockIdx.y * 32;
  int tx = threadIdx.x, ty = threadIdx.y;
  for (int j = ty; j < 32; j += 8)
    t[j][tx] = W[(size_t)(k0 + j) * N + n0 + tx];
  __syncthreads();
  for (int j = ty; j < 32; j += 8)
    Wt[(size_t)(n0 + j) * K + k0 + tx] = f2b(t[tx][j]);
}

// ---------------- GEMM: C[M][N] fp32 = A[M][K] bf16 * Bt[N][K] bf16 ----------------
__global__ __launch_bounds__(256, 3)
void k_gemm(const u16* __restrict__ A, const u16* __restrict__ Bt,
            float* __restrict__ C, int M, int N, int K) {
  __shared__ char smem[128 * 128 + 128 * 128];
  char* As = smem;
  char* Bs = smem + 128 * 128;
  const int tid = threadIdx.x;
  const int lane = tid & 63, wave = tid >> 6;
  const int l16 = lane & 15, lhi = lane >> 4;
  const int wm = (wave >> 1) * 64, wn = (wave & 1) * 64;
  const int bm = blockIdx.y, bn = blockIdx.x;
  const u16* Ab = A + (size_t)bm * 128 * K;
  const u16* Bb = Bt + (size_t)bn * 128 * K;
  f32x4 acc[4][4] = {};
  for (int k0 = 0; k0 < K; k0 += 64) {
    for (int p = 0; p < 4; ++p) {
      int r0 = wave * 32 + p * 8;
      int row = r0 + (lane >> 3);
      int src_off = ((lane & 7) * 16) ^ ((row & 7) << 4);
      const char* ga = (const char*)(Ab + (size_t)row * K + k0) + src_off;
      const char* gb = (const char*)(Bb + (size_t)row * K + k0) + src_off;
      __builtin_amdgcn_global_load_lds(
          (const __attribute__((address_space(1))) void*)ga,
          (__attribute__((address_space(3))) void*)(As + r0 * 128), 16, 0, 0);
      __builtin_amdgcn_global_load_lds(
          (const __attribute__((address_space(1))) void*)gb,
          (__attribute__((address_space(3))) void*)(Bs + r0 * 128), 16, 0, 0);
    }
    __syncthreads();
    for (int ks = 0; ks < 2; ++ks) {
      bf16x8 af[4], bfr[4];
      for (int f = 0; f < 4; ++f) {
        int m = wm + f * 16 + l16;
        af[f] = *reinterpret_cast<const bf16x8*>(As + m * 128 + ((ks * 64 + lhi * 16) ^ ((m & 7) << 4)));
        int n = wn + f * 16 + l16;
        bfr[f] = *reinterpret_cast<const bf16x8*>(Bs + n * 128 + ((ks * 64 + lhi * 16) ^ ((n & 7) << 4)));
      }
      for (int i = 0; i < 4; ++i)
        for (int j = 0; j < 4; ++j)
          acc[i][j] = __builtin_amdgcn_mfma_f32_16x16x32_bf16(af[i], bfr[j], acc[i][j], 0, 0, 0);
    }
    __syncthreads();
  }
  for (int i = 0; i < 4; ++i) {
    int m0 = bm * 128 + wm + i * 16 + lhi * 4;
    for (int j = 0; j < 4; ++j) {
      int n0 = bn * 128 + wn + j * 16 + l16;
      for (int r = 0; r < 4; ++r)
        C[(size_t)(m0 + r) * N + n0] = acc[i][j][r];
    }
  }
}

// ---------------- RoPE + row-norm capture ----------------
// pre[B*S][rowstride] fp32 -> outb[(b*nh+h)*S+s][128] bf16.
// RoPE preserves row norms, so norm computed from pre-rotation values.
// qn (if non-null): per-row ||q|| fp32, indexed [(b*nh+h)*S+s].
// kn2max (if non-null): atomicMax of ||k||^2 (uint bits) per (b*nh+h).
__global__ void k_rope(const float* __restrict__ pre, const float* __restrict__ cosT,
                       const float* __restrict__ sinT, u16* __restrict__ outb,
                       float* __restrict__ qn, u32* __restrict__ kn2max,
                       int nh, int rowstride) {
  int idx = blockIdx.x;          // (b*S + s)*nh + h
  int h = idx % nh;
  int bs = idx / nh;
  int b = bs / S_, s = bs % S_;
  int d = threadIdx.x;           // 0..63
  const float* row = pre + (size_t)bs * rowstride + h * HD_;
  const float* cr = cosT + (size_t)bs * HD_;
  const float* sr = sinT + (size_t)bs * HD_;
  float v1 = row[d], v2 = row[d + 64];
  float c1 = cr[d], s1 = sr[d], c2 = cr[d + 64], s2 = sr[d + 64];
  u16* out = outb + (((size_t)b * nh + h) * S_ + s) * HD_;
  out[d]      = f2b(v1 * c1 - v2 * s1);
  out[d + 64] = f2b(v2 * c2 + v1 * s2);
  float nr2 = v1 * v1 + v2 * v2;
  for (int o = 1; o < 64; o <<= 1) nr2 += __shfl_xor(nr2, o);
  if (d == 0) {
    if (qn)     qn[((size_t)b * nh + h) * S_ + s] = sqrtf(nr2);
    if (kn2max) atomicMax(&kn2max[b * nh + h], __builtin_bit_cast(u32, nr2));
  }
}

// ---------------- V: kvpre[B*S][1024] cols 512.. fp32 -> vT[(b*HKV+h)*128+d][S] bf16 ----------------
__global__ void k_vT(const float* __restrict__ kvpre, u16* __restrict__ vT) {
  __shared__ float t[32][33];
  int s0 = blockIdx.x * 32, d0 = blockIdx.y * 32;
  int bh = blockIdx.z;
  int b = bh >> 2, hk = bh & 3;
  int tx = threadIdx.x, ty = threadIdx.y;
  for (int j = ty; j < 32; j += 8)
    t[j][tx] = kvpre[((size_t)b * S_ + s0 + j) * 1024 + 512 + hk * HD_ + d0 + tx];
  __syncthreads();
  for (int j = ty; j < 32; j += 8)
    vT[((size_t)bh * HD_ + d0 + j) * S_ + s0 + tx] = f2b(t[tx][j]);
}

// ---------------- Attention (single QK^T pass via Cauchy-Schwarz bound) ----------------
// Block = 16-row q-tile, 8 waves split the 32-key tiles round-robin.
// p_unnorm = exp(SCALE*q.k - M_row) <= e (M_row = SCALE*||q||*max||k||), stored
// bf16 in a 64KB XOR-swizzled LDS row-buffer; l accumulated; PV with unnormalized
// p; epilogue normalizes both attn (LDS->global, coalesced) and oh.
__global__ __launch_bounds__(512, 4)
void k_attn(const u16* __restrict__ qb, const u16* __restrict__ kb,
            const u16* __restrict__ vT, const float* __restrict__ qn,
            const u32* __restrict__ kn2max,
            float* __restrict__ attn, u16* __restrict__ oh) {
  __shared__ u16 pbuf[16 * 2048];       // 64KB p-tile rows (swizzled cols)
  __shared__ float red_l[8][16];
  __shared__ float rl[16];
  __shared__ f32x4 comb[8][64];         // 8KB PV combine

  const int tid = threadIdx.x;
  const int wave = tid >> 6, lane = tid & 63;
  const int l16 = lane & 15, lhi = lane >> 4;

  const int bid = blockIdx.x;
  const int qt = 127 - (bid >> 5);          // longest first
  const int bh = bid & 31;
  const int b = bh >> 4, h = bh & 15, hk = h >> 2;
  const int q0 = qt * 16;
  const int nt = (qt + 2) >> 1;             // # of 32-key tiles
  const int tmask = nt - 1;

  const u16* Q  = qb + ((size_t)(b * H_ + h) * S_) * HD_;
  const u16* Kr = kb + ((size_t)(b * HKV_ + hk) * S_) * HD_;
  const u16* Vt = vT + ((size_t)(b * HKV_ + hk) * HD_) * S_;
  float* attnp = attn + (size_t)(b * H_ + h) * S_ * S_;

  // exp-shift bound per lane-row
  const float kmax = sqrtf(__builtin_bit_cast(float, kn2max[b * HKV_ + hk]));
  float Mrow[4];
  #pragma unroll
  for (int r = 0; r < 4; ++r)
    Mrow[r] = SCALE_ * kmax * qn[((size_t)b * H_ + h) * S_ + q0 + lhi * 4 + r];

  bf16x8 qf[4];
  {
    const u16* qrow = Q + (size_t)(q0 + l16) * HD_ + lhi * 8;
    #pragma unroll
    for (int kd = 0; kd < 4; ++kd)
      qf[kd] = *reinterpret_cast<const bf16x8*>(qrow + kd * 32);
  }

  float l_l[4] = {0.f, 0.f, 0.f, 0.f};
  f32x4 oacc[8] = {};

  for (int t = wave; t < nt; t += 8) {
    int kt = t * 32;
    // QK^T
    f32x4 s0 = {0.f, 0.f, 0.f, 0.f}, s1 = {0.f, 0.f, 0.f, 0.f};
    {
      const u16* kp0 = Kr + (size_t)(kt + l16) * HD_ + lhi * 8;
      const u16* kp1 = kp0 + 16 * HD_;
      #pragma unroll
      for (int kd = 0; kd < 4; ++kd) {
        bf16x8 kf0 = *reinterpret_cast<const bf16x8*>(kp0 + kd * 32);
        bf16x8 kf1 = *reinterpret_cast<const bf16x8*>(kp1 + kd * 32);
        s0 = __builtin_amdgcn_mfma_f32_16x16x32_bf16(qf[kd], kf0, s0, 0, 0, 0);
        s1 = __builtin_amdgcn_mfma_f32_16x16x32_bf16(qf[kd], kf1, s1, 0, 0, 0);
      }
    }
    // p = exp(s - M), mask -> 0, store swizzled bf16, accumulate l
    bool mk = (t == tmask);
    #pragma unroll
    for (int r = 0; r < 4; ++r) {
      int rr = lhi * 4 + r;
      float p0 = __expf(s0[r] * SCALE_ - Mrow[r]);
      float p1 = __expf(s1[r] * SCALE_ - Mrow[r]);
      if (mk) {
        int row = q0 + rr;
        p0 = (kt + l16)      > row ? 0.f : p0;
        p1 = (kt + 16 + l16) > row ? 0.f : p1;
      }
      l_l[r] += p0 + p1;
      int sw = (rr & 7) << 3;
      pbuf[rr * 2048 + ((kt + l16) ^ sw)]      = f2b(p0);
      pbuf[rr * 2048 + ((kt + 16 + l16) ^ sw)] = f2b(p1);
    }
    // PV: transpose read of own tile (same-wave RAW; lgkmcnt handles it)
    bf16x8 pa = *reinterpret_cast<const bf16x8*>(
        &pbuf[l16 * 2048 + ((kt + lhi * 8) ^ ((l16 & 7) << 3))]);
    #pragma unroll
    for (int dt = 0; dt < 8; ++dt) {
      const u16* vp = Vt + (size_t)(dt * 16 + l16) * S_ + kt + lhi * 8;
      bf16x8 vf = *reinterpret_cast<const bf16x8*>(vp);
      oacc[dt] = __builtin_amdgcn_mfma_f32_16x16x32_bf16(pa, vf, oacc[dt], 0, 0, 0);
    }
  }

  // ---- l reduction: 16 lanes -> cross-wave ----
  #pragma unroll
  for (int r = 0; r < 4; ++r) {
    float ll = l_l[r];
    for (int o = 1; o < 16; o <<= 1) ll += __shfl_xor(ll, o);
    if (l16 == 0) red_l[wave][lhi * 4 + r] = ll;
  }
  __syncthreads();
  if (wave == 0 && lane < 16) {
    float ll = 0.f;
    #pragma unroll
    for (int w = 0; w < 8; ++w) ll += red_l[w][lane];
    rl[lane] = 1.f / ll;
  }
  __syncthreads();

  // ---- attn write: normalize from LDS, coalesced (32 threads/row) ----
  {
    int row = tid >> 5;                 // 0..15
    int sw = (row & 7) << 3;
    float rinv = rl[row];
    float* dst = attnp + (size_t)(q0 + row) * S_;
    for (int cb = (tid & 31) * 8; cb < 32 * nt; cb += 256) {
      bf16x8 pv8 = *reinterpret_cast<const bf16x8*>(&pbuf[row * 2048 + (cb ^ sw)]);
      const u16* pu = reinterpret_cast<const u16*>(&pv8);
      float4 w0, w1;
      w0.x = b2f(pu[0]) * rinv; w0.y = b2f(pu[1]) * rinv;
      w0.z = b2f(pu[2]) * rinv; w0.w = b2f(pu[3]) * rinv;
      w1.x = b2f(pu[4]) * rinv; w1.y = b2f(pu[5]) * rinv;
      w1.z = b2f(pu[6]) * rinv; w1.w = b2f(pu[7]) * rinv;
      *reinterpret_cast<float4*>(dst + cb)     = w0;
      *reinterpret_cast<float4*>(dst + cb + 4) = w1;
    }
    // zero-fill [32*nt, S)
    float4 z = make_float4(0.f, 0.f, 0.f, 0.f);
    for (int c = 32 * nt + (tid & 31) * 4; c < S_; c += 128)
      *reinterpret_cast<float4*>(dst + c) = z;
  }

  // ---- PV combine across 8 waves (8 rounds) + oh write ----
  for (int dt = 0; dt < 8; ++dt) {
    __syncthreads();
    comb[wave][lane] = oacc[dt];
    __syncthreads();
    if (wave == 0) {
      f32x4 s = comb[0][lane];
      #pragma unroll
      for (int w = 1; w < 8; ++w) s += comb[w][lane];
      #pragma unroll
      for (int r = 0; r < 4; ++r) {
        int rr = lhi * 4 + r;
        oh[((size_t)b * S_ + q0 + rr) * (H_ * HD_) + h * HD_ + dt * 16 + l16] =
            f2b(s[r] * rl[rr]);
      }
    }
  }
}

extern "C" void kernel_launch(void* const* d_in, const int* in_sizes, int n_in,
                              void* d_out, int out_size, void* d_ws, size_t ws_size,
                              hipStream_t stream) {
  const float* x    = (const float*)d_in[0];
  const float* cosT = (const float*)d_in[1];
  const float* sinT = (const float*)d_in[2];
  // d_in[3] = attention_mask: pure causal, reconstructed in-kernel
  const float* Wq = (const float*)d_in[4];
  const float* Wk = (const float*)d_in[5];
  const float* Wv = (const float*)d_in[6];
  const float* Wo = (const float*)d_in[7];
  float* out  = (float*)d_out;
  float* attn = out + (size_t)B_ * S_ * D_;

  char* ws = (char*)d_ws;
  u16*   xb    = (u16*)(ws);                       // 16,777,216 B
  u16*   wqT   = (u16*)(ws + 16777216);            //  8,388,608
  u16*   wkvT  = (u16*)(ws + 25165824);            //  4,194,304 (K rows 0..511, V rows 512..1023)
  u16*   woT   = (u16*)(ws + 29360128);            //  8,388,608
  float* qpre  = (float*)(ws + 37748736);          // 33,554,432
  float* kvpre = (float*)(ws + 71303168);          // 16,777,216
  u16*   qb    = (u16*)(ws + 88080384);            // 16,777,216
  u16*   kb    = (u16*)(ws + 104857600);           //  4,194,304
  u16*   vT    = (u16*)(ws + 109051904);           //  4,194,304
  u16*   oh    = (u16*)(ws + 113246208);           // 16,777,216  (end ~130 MB)
  // qn/knm reuse the xb region: xb is dead after the two projection GEMMs,
  // and k_rope (which writes these) runs after them. Rewritten every call.
  float* qn    = (float*)(ws);                     // 262,144 B (B*S*H)
  u32*   knm   = (u32*)(ws + 1048576);             // 32 B

  // 1) dtype prep
  k_f2b<<<8192, 256, 0, stream>>>(x, xb);
  k_wT<<<dim3(64, 64), dim3(32, 8), 0, stream>>>(Wq, wqT, 2048, 2048);
  k_wT<<<dim3(16, 64), dim3(32, 8), 0, stream>>>(Wk, wkvT, 2048, 512);
  k_wT<<<dim3(16, 64), dim3(32, 8), 0, stream>>>(Wv, wkvT + (size_t)512 * 2048, 2048, 512);
  k_wT<<<dim3(64, 64), dim3(32, 8), 0, stream>>>(Wo, woT, 2048, 2048);

  // 2) projections: Q (N=2048) and fused K|V (N=1024)
  k_gemm<<<dim3(16, 32), 256, 0, stream>>>(xb, wqT, qpre, 4096, 2048, 2048);
  k_gemm<<<dim3(8, 32), 256, 0, stream>>>(xb, wkvT, kvpre, 4096, 1024, 2048);

  // 3) RoPE + layout conversion to bf16 (+ norm capture); xb is free now
  k_init8<<<1, 64, 0, stream>>>(knm);
  k_rope<<<B_ * S_ * H_, 64, 0, stream>>>(qpre, cosT, sinT, qb, qn, nullptr, H_, 2048);
  k_rope<<<B_ * S_ * HKV_, 64, 0, stream>>>(kvpre, cosT, sinT, kb, nullptr, knm, HKV_, 1024);
  k_vT<<<dim3(64, 4, B_ * HKV_), dim3(32, 8), 0, stream>>>(kvpre, vT);

  // 4) attention (single-pass; writes attn fp32 incl. zeros, oh bf16)
  k_attn<<<4096, 512, 0, stream>>>(qb, kb, vT, qn, knm, attn, oh);

  // 5) output projection
  k_gemm<<<dim3(16, 32), 256, 0, stream>>>(oh, woT, out, 4096, 2048, 2048);
}